// Round 7
// baseline (143.851 us; speedup 1.0000x reference)
//
#include <hip/hip_runtime.h>
#include <math.h>

#define SEQ   3000
#define FDIM  64
// 999 sequential steps = 111 groups (g0..g110) x 9 steps.
// 128 blocks x 64 threads, one (b,f) chain per lane. All vmem is inline asm:
// double-buffered prefetch loads 1 group ahead, counted s_waitcnt vmcnt(N)
// (never 0 in the loop), stores issued directly from the 3 state registers
// (VMEM stores latch data at issue -> immediate register reuse is safe).

#define ISQ  0.70710678118654752440f
#define PP   0.3275911f
#define B1c  0.127414796f      // 0.5*0.254829592
#define B2c  (-0.142248368f)   // 0.5*-0.284496736
#define B3c  0.7107068705f     // 0.5*1.421413741
#define B4c  (-0.7265760135f)  // 0.5*-1.453152027
#define B5c  0.5307027145f     // 0.5*1.061405429
#define NL2E (-0.72134752044448170368f)   // -0.5*log2(e)

#define DECL27(p)  float p##0,p##1,p##2,p##3,p##4,p##5,p##6,p##7,p##8,p##9,   \
    p##10,p##11,p##12,p##13,p##14,p##15,p##16,p##17,p##18,p##19,p##20,p##21,  \
    p##22,p##23,p##24,p##25,p##26

#define TOUCH27(P) "+v"(P##0),"+v"(P##1),"+v"(P##2),"+v"(P##3),"+v"(P##4),    \
    "+v"(P##5),"+v"(P##6),"+v"(P##7),"+v"(P##8),"+v"(P##9),"+v"(P##10),       \
    "+v"(P##11),"+v"(P##12),"+v"(P##13),"+v"(P##14),"+v"(P##15),"+v"(P##16),  \
    "+v"(P##17),"+v"(P##18),"+v"(P##19),"+v"(P##20),"+v"(P##21),"+v"(P##22),  \
    "+v"(P##23),"+v"(P##24),"+v"(P##25),"+v"(P##26)

#define PF1(dst, p, OFF)                                                      \
    asm volatile("global_load_dword %0, %1, off offset:" #OFF                 \
                 : "=v"(dst) : "v"(p) : "memory")
#define ST1(val, p, OFF)                                                      \
    asm volatile("global_store_dword %0, %1, off offset:" #OFF                \
                 :: "v"(p), "v"(val) : "memory")

// 27 loads of one group; xc advances 9 rows (2304 B) per 9 loads so every
// offset immediate stays < 4096.
#define PF27(P) do {                                                          \
    PF1(P##0,  xc, 0);    PF1(P##1,  xc, 256);  PF1(P##2,  xc, 512);          \
    PF1(P##3,  xc, 768);  PF1(P##4,  xc, 1024); PF1(P##5,  xc, 1280);         \
    PF1(P##6,  xc, 1536); PF1(P##7,  xc, 1792); PF1(P##8,  xc, 2048);         \
    xc += 9 * FDIM;                                                           \
    PF1(P##9,  xc, 0);    PF1(P##10, xc, 256);  PF1(P##11, xc, 512);          \
    PF1(P##12, xc, 768);  PF1(P##13, xc, 1024); PF1(P##14, xc, 1280);         \
    PF1(P##15, xc, 1536); PF1(P##16, xc, 1792); PF1(P##17, xc, 2048);         \
    xc += 9 * FDIM;                                                           \
    PF1(P##18, xc, 0);    PF1(P##19, xc, 256);  PF1(P##20, xc, 512);          \
    PF1(P##21, xc, 768);  PF1(P##22, xc, 1024); PF1(P##23, xc, 1280);         \
    PF1(P##24, xc, 1536); PF1(P##25, xc, 1792); PF1(P##26, xc, 2048);         \
    xc += 9 * FDIM;                                                           \
} while (0)

// counted wait: P = load buffer about to be consumed; dataflow tie so its
// consumers cannot hoist above the wait (rule #18), plus a sched fence.
#define WAITVM(Nlit, P) do {                                                  \
    asm volatile("s_waitcnt vmcnt(" #Nlit ")" : TOUCH27(P) : : "memory");     \
    __builtin_amdgcn_sched_barrier(0);                                        \
} while (0)

// One scan step, hand-staged 3-wide so the in-order schedule interleaves the
// three channels (each stage: ch0, ch1, ch2). exp path first (longest indep
// latency). |a| via free src modifiers: a*a, and -|a| folds into final fma.
// New state s0..s2 are the outputs; stored immediately, reused next step.
#define GSTEP3(F0, F1, F2, u0, u1, u2) do {                                   \
    float a0 = fmaf(s2, w02, fmaf(s1, w01, fmaf(s0, w00, q0)));               \
    float a1 = fmaf(s2, w12, fmaf(s1, w11, fmaf(s0, w10, q1)));               \
    float a2 = fmaf(s2, w22, fmaf(s1, w21, fmaf(s0, w20, q2)));               \
    float g0 = a0 * a0, g1 = a1 * a1, g2 = a2 * a2;                           \
    float m0 = g0 * NL2E, m1 = g1 * NL2E, m2 = g2 * NL2E;                     \
    float e0 = __builtin_amdgcn_exp2f(m0);                                    \
    float e1 = __builtin_amdgcn_exp2f(m1);                                    \
    float e2 = __builtin_amdgcn_exp2f(m2);                                    \
    float t0 = fabsf(a0) * ISQ, t1 = fabsf(a1) * ISQ, t2 = fabsf(a2) * ISQ;   \
    float d0 = fmaf(PP, t0, 1.0f), d1 = fmaf(PP, t1, 1.0f),                   \
          d2 = fmaf(PP, t2, 1.0f);                                            \
    float r0 = __builtin_amdgcn_rcpf(d0);                                     \
    float r1 = __builtin_amdgcn_rcpf(d1);                                     \
    float r2 = __builtin_amdgcn_rcpf(d2);                                     \
    float p0 = fmaf(B2c, r0, B1c), p1 = fmaf(B2c, r1, B1c),                   \
          p2 = fmaf(B2c, r2, B1c);                                            \
    float n0 = fmaf(B4c, r0, B3c), n1 = fmaf(B4c, r1, B3c),                   \
          n2 = fmaf(B4c, r2, B3c);                                            \
    float rr0 = r0 * r0, rr1 = r1 * r1, rr2 = r2 * r2;                        \
    p0 = fmaf(n0, rr0, p0); p1 = fmaf(n1, rr1, p1); p2 = fmaf(n2, rr2, p2);   \
    float r40 = rr0 * rr0, r41 = rr1 * rr1, r42 = rr2 * rr2;                  \
    p0 = fmaf(B5c, r40, p0); p1 = fmaf(B5c, r41, p1); p2 = fmaf(B5c, r42, p2);\
    p0 = p0 * r0; p1 = p1 * r1; p2 = p2 * r2;                                 \
    float er0 = p0 * e0, er1 = p1 * e1, er2 = p2 * e2;                        \
    s0 = fmaf(-fabsf(a0), er0, fmaxf(a0, 0.0f)) + u0;                         \
    s1 = fmaf(-fabsf(a1), er1, fmaxf(a1, 0.0f)) + u1;                         \
    s2 = fmaf(-fabsf(a2), er2, fmaxf(a2, 0.0f)) + u2;                         \
    ST1(s0, oc, F0); ST1(s1, oc, F1); ST1(s2, oc, F2);                        \
} while (0)

// one group of 9 steps; 27 asm stores; oc advances 9 rows per 3 steps
#define COMPUTE_GRP(P) do {                                                   \
    GSTEP3(0, 256, 512,      P##0,  P##1,  P##2);                             \
    GSTEP3(768, 1024, 1280,  P##3,  P##4,  P##5);                             \
    GSTEP3(1536, 1792, 2048, P##6,  P##7,  P##8);                             \
    oc += 9 * FDIM;                                                           \
    GSTEP3(0, 256, 512,      P##9,  P##10, P##11);                            \
    GSTEP3(768, 1024, 1280,  P##12, P##13, P##14);                            \
    GSTEP3(1536, 1792, 2048, P##15, P##16, P##17);                            \
    oc += 9 * FDIM;                                                           \
    GSTEP3(0, 256, 512,      P##18, P##19, P##20);                            \
    GSTEP3(768, 1024, 1280,  P##21, P##22, P##23);                            \
    GSTEP3(1536, 1792, 2048, P##24, P##25, P##26);                            \
    oc += 9 * FDIM;                                                           \
} while (0)

__global__ __launch_bounds__(64, 1) void scan_kernel(
    const float* __restrict__ x,
    const float* __restrict__ w,
    const float* __restrict__ bias,
    float* __restrict__ out)
{
    const int b = blockIdx.x;
    const int f = threadIdx.x;

    const float w00 = w[0], w01 = w[1], w02 = w[2];
    const float w10 = w[3], w11 = w[4], w12 = w[5];
    const float w20 = w[6], w21 = w[7], w22 = w[8];
    const float q0 = bias[0], q1 = bias[1], q2 = bias[2];

    const float* __restrict__ xp = x   + (size_t)b * (SEQ * FDIM) + f;
    float*       __restrict__ op = out + (size_t)b * (SEQ * FDIM) + f;

    // head: plain loads, consumed by the touch so the compiler's own vmcnt
    // wait lands HERE (before any asm loads are outstanding)
    float s0 = xp[0 * FDIM], s1 = xp[1 * FDIM], s2 = xp[2 * FDIM];
    asm volatile("" : "+v"(s0), "+v"(s1), "+v"(s2));
    ST1(s0, op, 0); ST1(s1, op, 256); ST1(s2, op, 512);   // 3 asm stores

    const float* xc = xp + 3 * FDIM;
    float*       oc = op + 3 * FDIM;

    DECL27(LA); DECL27(LB);     // load double-buffer (asm outputs)

    PF27(LA);                   // g0
    PF27(LB);                   // g1
    // outstanding: hst(3) + LA(27) + LB(27) = 57 -> vmcnt(27) retires hst+LA
    WAITVM(27, LA);

    // loop t: computes g=2t (LA) and g=2t+1 (LB); prefetches 2t+2, 2t+3
    #pragma unroll 1
    for (int t = 0; t < 54; ++t) {
        COMPUTE_GRP(LA);        // g = 2t      (27 stores)
        PF27(LA);               // g = 2t+2    (27 loads)
        // young 54 = st(2t) + LA(2t+2): all older retired -> LB(2t+1) ready
        WAITVM(54, LB);
        COMPUTE_GRP(LB);        // g = 2t+1
        PF27(LB);               // g = 2t+3
        WAITVM(54, LA);         // LA(2t+2) ready
    }

    // epilogue: g108 (in LA), g109 (in LB), g110
    COMPUTE_GRP(LA);            // g108
    PF27(LA);                   // g110
    WAITVM(54, LB);             // LB = g109 ready
    COMPUTE_GRP(LB);            // g109
    WAITVM(27, LA);             // young 27 = st(g109) -> LA = g110 ready
    COMPUTE_GRP(LA);            // g110
}

extern "C" void kernel_launch(void* const* d_in, const int* in_sizes, int n_in,
                              void* d_out, int out_size, void* d_ws, size_t ws_size,
                              hipStream_t stream) {
    const float* x    = (const float*)d_in[0];
    const float* w    = (const float*)d_in[1];
    const float* bias = (const float*)d_in[2];
    float* out        = (float*)d_out;

    hipLaunchKernelGGL(scan_kernel, dim3(128), dim3(FDIM), 0, stream,
                       x, w, bias, out);
}